// Round 16
// baseline (788.272 us; speedup 1.0000x reference)
//
#include <hip/hip_runtime.h>
#include <hip/hip_bf16.h>

#define N_COARSE 12500
#define N_FINE   50000

typedef __bf16 bf16x8 __attribute__((ext_vector_type(8)));
typedef __bf16 bf16x4 __attribute__((ext_vector_type(4)));
typedef float  f32x4  __attribute__((ext_vector_type(4)));

// ---------------------------------------------------------------------------
// Fragment conventions (v_mfma_f32_16x16x32_bf16), HW-verified:
//   a-frag: lane holds A[row = lane&15][k = (lane>>4)*8 + j]
//   b-frag: lane holds B[k = (lane>>4)*8 + j][col = lane&15]
//   d     : lane holds D[row = (lane>>4)*4 + j][col = lane&15]
// ---------------------------------------------------------------------------

__device__ __forceinline__ bf16x8 cvt8(f32x4 x, f32x4 y) {
    bf16x8 r;
    r[0] = (__bf16)x[0]; r[1] = (__bf16)x[1]; r[2] = (__bf16)x[2]; r[3] = (__bf16)x[3];
    r[4] = (__bf16)y[0]; r[5] = (__bf16)y[1]; r[6] = (__bf16)y[2]; r[7] = (__bf16)y[3];
    return r;
}

// Barrier with LDS-only fence (avoids __syncthreads' vmcnt(0) drain).
__device__ __forceinline__ void lds_barrier() {
    asm volatile("s_waitcnt lgkmcnt(0)" ::: "memory");
    __builtin_amdgcn_s_barrier();
}

// ---- LDS A-tile, XOR-swizzled (row stride 512 B) --------------------------
__device__ __forceinline__ int swz(int row, int byte) { return byte ^ ((row & 7) << 4); }
__device__ __forceinline__ void st_a(__bf16* lds, int row, int cs, bf16x8 v) {
    *(bf16x8*)((char*)lds + swz(row, row * 512 + cs * 16)) = v;
}
__device__ __forceinline__ bf16x8 ld_a(const __bf16* lds, int row, int ka) {
    return *(const bf16x8*)((const char*)lds + swz(row, row * 512 + ka * 2));
}

// stage ROWS consecutive f32 rows (256 cols) -> bf16 LDS tile; coalesced
template<int ROWS, int NT>
__device__ __forceinline__ void stage_f32(const float* __restrict__ A, long row0,
                                          __bf16* lds, int tid, long maxrow) {
    const int r0 = tid >> 5, cs = tid & 31;
    constexpr int RPI = NT / 32;
    #pragma unroll
    for (int i = 0; i < ROWS / RPI; ++i) {
        int row = r0 + i * RPI;
        long gr = row0 + row; if (gr > maxrow) gr = maxrow;
        const float* p = A + gr * 256 + cs * 8;
        f32x4 x = *(const f32x4*)p, y = *(const f32x4*)(p + 4);
        st_a(lds, row, cs, cvt8(x, y));
    }
}

// (RT*16)x64-per-wave MFMA over one 256-wide K segment, A from LDS
template<int RT>
__device__ __forceinline__ void mfma_tile(const __bf16* lds, const bf16x8* __restrict__ packB,
                                          int N, int c0, int ksb,
                                          f32x4 (&acc)[RT][4], int lane) {
    const int g = lane >> 4, r15 = lane & 15;
    #pragma unroll
    for (int ks = 0; ks < 8; ++ks) {
        bf16x8 a[RT];
        #pragma unroll
        for (int rt = 0; rt < RT; ++rt)
            a[rt] = ld_a(lds, rt * 16 + r15, ks * 32 + g * 8);
        const size_t kb = (size_t)((ksb + ks) * 4 + g) * N;
        #pragma unroll
        for (int ct = 0; ct < 4; ++ct) {
            bf16x8 b = packB[kb + c0 + ct * 16 + r15];
            #pragma unroll
            for (int rt = 0; rt < RT; ++rt)
                acc[rt][ct] = __builtin_amdgcn_mfma_f32_16x16x32_bf16(a[rt], b, acc[rt][ct], 0, 0, 0);
        }
    }
}

// ---------------------------------------------------------------------------
// Merged prep: pack W_le / W_ce / W_mlp into MFMA b-frag layout + cvt last_inv
// to bf16. Pack layout: dst[((k>>3)*N + n)*8 + (k&7)] = (bf16)W[k*N + n]
// ---------------------------------------------------------------------------
__global__ __launch_bounds__(256) void k_prep(
    const float* __restrict__ W_le, const float* __restrict__ W_ce,
    const float* __restrict__ W_mlp, const float* __restrict__ last_inv,
    __bf16* __restrict__ packLE, __bf16* __restrict__ packCE,
    __bf16* __restrict__ packM, __bf16* __restrict__ li_bf)
{
    const int b = blockIdx.x, tid = threadIdx.x;
    if (b < 256) {                       // W_le pack (256x256)
        int idx = b * 256 + tid, k = idx >> 8, n = idx & 255;
        packLE[(((size_t)(k >> 3) << 8) + n) * 8 + (k & 7)] = (__bf16)W_le[idx];
    } else if (b < 512) {                // W_ce pack (256x256)
        int idx = (b - 256) * 256 + tid, k = idx >> 8, n = idx & 255;
        packCE[(((size_t)(k >> 3) << 8) + n) * 8 + (k & 7)] = (__bf16)W_ce[idx];
    } else if (b < 2048) {               // W_mlp pack (768x512)
        int idx = (b - 512) * 256 + tid, k = idx >> 9, n = idx & 511;
        packM[(((size_t)(k >> 3) << 9) + n) * 8 + (k & 7)] = (__bf16)W_mlp[idx];
    } else {                             // last_inv f32 -> bf16
        int i = (b - 2048) * 256 + tid;
        f32x4 v = ((const f32x4*)last_inv)[i];
        bf16x4 o;
        o[0] = (__bf16)v[0]; o[1] = (__bf16)v[1]; o[2] = (__bf16)v[2]; o[3] = (__bf16)v[3];
        ((bf16x4*)li_bf)[i] = o;
    }
}

// ---------------------------------------------------------------------------
// Coarse: LE = last_equ @ W_last_equ -> LEp (MFMA D-layout, bf16).
// 32-row tiles (2 coarse points), 16 KB LDS, ~70 VGPR -> 6 blocks/CU pinned:
// more desynchronized stagers per CU (the R13-proven TLP lever, pushed).
// ---------------------------------------------------------------------------
__global__ __launch_bounds__(256, 6) void k_coarse_equ(
    const float* __restrict__ last_equ, const bf16x8* __restrict__ packW,
    __bf16* __restrict__ LEp)
{
    __shared__ __attribute__((aligned(16))) __bf16 As[32 * 256];
    const int tid = threadIdx.x, lane = tid & 63, wid = tid >> 6;
    for (int t = blockIdx.x; t < N_COARSE * 16 / 32; t += gridDim.x) {
        stage_f32<32, 256>(last_equ, (long)t * 32, As, tid, (long)N_COARSE * 16 - 1);
        lds_barrier();
        f32x4 acc[2][4] = {};
        mfma_tile<2>(As, packW, 256, wid * 64, 0, acc, lane);
        #pragma unroll
        for (int rt = 0; rt < 2; ++rt) {
            int coarse = t * 2 + rt;
            #pragma unroll
            for (int ct = 0; ct < 4; ++ct) {
                int cg = wid * 4 + ct;
                bf16x4 v;
                v[0] = (__bf16)acc[rt][ct][0]; v[1] = (__bf16)acc[rt][ct][1];
                v[2] = (__bf16)acc[rt][ct][2]; v[3] = (__bf16)acc[rt][ct][3];
                *(bf16x4*)(LEp + ((size_t)(coarse * 16 + cg) * 64 + lane) * 4) = v;
            }
        }
        lds_barrier();   // As reads done before next iteration overwrites
    }
}

// ---------------------------------------------------------------------------
// Fine fused: 32-row tiles (2 fine points), 16 KB LDS, ~70 VGPR, 6 blocks/CU.
// Body logic identical to R13 (stage -> lgkm barrier -> MFMA -> post-MFMA LE
// gathers -> product -> basis-mean -> store); per-point math order unchanged.
// ---------------------------------------------------------------------------
__global__ __launch_bounds__(256, 6) void k_fine_equ(
    const float* __restrict__ cur_equ, const bf16x8* __restrict__ packW,
    const __bf16* __restrict__ LEp, const int* __restrict__ up,
    __bf16* __restrict__ equ)
{
    __shared__ __attribute__((aligned(16))) __bf16 As[32 * 256];
    const int tid = threadIdx.x, lane = tid & 63, wid = tid >> 6;
    for (int t = blockIdx.x; t < N_FINE / 2; t += gridDim.x) {
        const int n0 = t * 2;
        int cu[2];
        cu[0] = up[n0]; cu[1] = up[n0 + 1];        // uniform -> s_load

        stage_f32<32, 256>(cur_equ, (long)t * 32, As, tid, (long)N_FINE * 16 - 1);
        lds_barrier();

        f32x4 acc[2][4] = {};
        mfma_tile<2>(As, packW, 256, wid * 64, 0, acc, lane);

        // LE fragment gathers post-MFMA (VGPRs not live across the GEMM)
        bf16x4 le[2][4];
        #pragma unroll
        for (int rt = 0; rt < 2; ++rt)
            #pragma unroll
            for (int ct = 0; ct < 4; ++ct)
                le[rt][ct] = *(const bf16x4*)(LEp +
                    ((size_t)(cu[rt] * 16 + wid * 4 + ct) * 64 + lane) * 4);

        #pragma unroll
        for (int rt = 0; rt < 2; ++rt) {
            int n = n0 + rt;
            #pragma unroll
            for (int ct = 0; ct < 4; ++ct) {
                float s = acc[rt][ct][0] * (float)le[rt][ct][0]
                        + acc[rt][ct][1] * (float)le[rt][ct][1]
                        + acc[rt][ct][2] * (float)le[rt][ct][2]
                        + acc[rt][ct][3] * (float)le[rt][ct][3];
                s += __shfl_xor(s, 16, 64);   // basis reduce over lane bit 4
                s += __shfl_xor(s, 32, 64);   // basis reduce over lane bit 5
                if (lane < 16)
                    equ[(size_t)n * 256 + wid * 64 + ct * 16 + lane] =
                        (__bf16)(s * 0.0625f);
            }
        }
        lds_barrier();   // As reads done before next iteration overwrites
    }
}

// ---------------------------------------------------------------------------
// Output: out = [ last_inv[up] | cur_inv | equ ] @ W_mlp  (K=768).
// R13 one-shot form (persistent variant measured flat-to-negative in R15).
// ---------------------------------------------------------------------------
__global__ __launch_bounds__(512) void k_out(
    const __bf16* __restrict__ li_bf, const float* __restrict__ cur_inv,
    const __bf16* __restrict__ equ, const bf16x8* __restrict__ packW,
    const int* __restrict__ up, float* __restrict__ out)
{
    __shared__ __attribute__((aligned(16))) __bf16 As[64 * 256];
    const int tid = threadIdx.x, lane = tid & 63, wid = tid >> 6;
    const int row0 = blockIdx.x * 64;
    const int c0 = wid * 64;
    const int r0 = tid >> 5, cs = tid & 31;
    f32x4 acc[4][4] = {};

    // seg0: gathered last_inv rows (bf16)
    #pragma unroll
    for (int i = 0; i < 4; ++i) {
        int row = r0 + i * 16;
        int gr = row0 + row; if (gr > N_FINE - 1) gr = N_FINE - 1;
        st_a(As, row, cs, *(const bf16x8*)(li_bf + (size_t)up[gr] * 256 + cs * 8));
    }
    lds_barrier();
    mfma_tile<4>(As, packW, 512, c0, 0, acc, lane);
    lds_barrier();

    // seg1: cur_inv (f32)
    stage_f32<64, 512>(cur_inv, row0, As, tid, N_FINE - 1);
    lds_barrier();
    mfma_tile<4>(As, packW, 512, c0, 8, acc, lane);
    lds_barrier();

    // seg2: equ (bf16)
    #pragma unroll
    for (int i = 0; i < 4; ++i) {
        int row = r0 + i * 16;
        int gr = row0 + row; if (gr > N_FINE - 1) gr = N_FINE - 1;
        st_a(As, row, cs, *(const bf16x8*)(equ + (size_t)gr * 256 + cs * 8));
    }
    lds_barrier();
    mfma_tile<4>(As, packW, 512, c0, 16, acc, lane);

    const int g = lane >> 4, r15 = lane & 15;
    #pragma unroll
    for (int rt = 0; rt < 4; ++rt)
        #pragma unroll
        for (int j = 0; j < 4; ++j) {
            int r = row0 + rt * 16 + g * 4 + j;
            if (r < N_FINE)
                #pragma unroll
                for (int ct = 0; ct < 4; ++ct)
                    out[(size_t)r * 512 + c0 + ct * 16 + r15] = acc[rt][ct][j];
        }
}

extern "C" void kernel_launch(void* const* d_in, const int* in_sizes, int n_in,
                              void* d_out, int out_size, void* d_ws, size_t ws_size,
                              hipStream_t stream) {
    const float* last_inv = (const float*)d_in[0];
    const float* cur_inv  = (const float*)d_in[1];
    const float* last_equ = (const float*)d_in[2];
    const float* cur_equ  = (const float*)d_in[3];
    const int*   up       = (const int*)d_in[4];
    const float* W_le     = (const float*)d_in[5];
    const float* W_ce     = (const float*)d_in[6];
    const float* W_mlp    = (const float*)d_in[7];
    float* out = (float*)d_out;

    // workspace carve-up (~135 MB)
    char* w = (char*)d_ws;
    __bf16* LEp    = (__bf16*)w;  w += (size_t)N_COARSE * 16 * 256 * 2;  // 102.4 MB
    __bf16* equ    = (__bf16*)w;  w += (size_t)N_FINE * 256 * 2;        //  25.6 MB
    __bf16* li_bf  = (__bf16*)w;  w += (size_t)N_COARSE * 256 * 2;      //   6.4 MB
    __bf16* packLE = (__bf16*)w;  w += (size_t)256 * 256 * 2;
    __bf16* packCE = (__bf16*)w;  w += (size_t)256 * 256 * 2;
    __bf16* packM  = (__bf16*)w;  w += (size_t)768 * 512 * 2;

    k_prep<<<2048 + 3125, 256, 0, stream>>>(
        W_le, W_ce, W_mlp, last_inv, packLE, packCE, packM, li_bf);

    // persistent grids: 6 blocks/CU x 256 CUs = 1536 (pinned by launch_bounds)
    k_coarse_equ<<<1536, 256, 0, stream>>>(
        last_equ, (const bf16x8*)packLE, LEp);

    k_fine_equ<<<1536, 256, 0, stream>>>(
        cur_equ, (const bf16x8*)packCE, LEp, up, equ);

    k_out<<<(N_FINE + 63) / 64, 512, 0, stream>>>(
        li_bf, cur_inv, equ, (const bf16x8*)packM, up, out);
}

// Round 17
// 516.394 us; speedup vs baseline: 1.5265x; 1.5265x over previous
//
#include <hip/hip_runtime.h>
#include <hip/hip_bf16.h>

#define N_COARSE 12500
#define N_FINE   50000

typedef __bf16 bf16x8 __attribute__((ext_vector_type(8)));
typedef __bf16 bf16x4 __attribute__((ext_vector_type(4)));
typedef float  f32x4  __attribute__((ext_vector_type(4)));

// ---------------------------------------------------------------------------
// Fragment conventions (v_mfma_f32_16x16x32_bf16), HW-verified:
//   a-frag: lane holds A[row = lane&15][k = (lane>>4)*8 + j]
//   b-frag: lane holds B[k = (lane>>4)*8 + j][col = lane&15]
//   d     : lane holds D[row = (lane>>4)*4 + j][col = lane&15]
// ---------------------------------------------------------------------------

__device__ __forceinline__ bf16x8 cvt8(f32x4 x, f32x4 y) {
    bf16x8 r;
    r[0] = (__bf16)x[0]; r[1] = (__bf16)x[1]; r[2] = (__bf16)x[2]; r[3] = (__bf16)x[3];
    r[4] = (__bf16)y[0]; r[5] = (__bf16)y[1]; r[6] = (__bf16)y[2]; r[7] = (__bf16)y[3];
    return r;
}

// Barrier with LDS-only fence (avoids __syncthreads' vmcnt(0) drain).
__device__ __forceinline__ void lds_barrier() {
    asm volatile("s_waitcnt lgkmcnt(0)" ::: "memory");
    __builtin_amdgcn_s_barrier();
}

// async global->LDS DMA, 16B per lane; LDS dest = uniform base + lane*16
__device__ __forceinline__ void gl_lds16(const float* g, float* l) {
    __builtin_amdgcn_global_load_lds(
        (const __attribute__((address_space(1))) void*)g,
        (__attribute__((address_space(3))) void*)l, 16, 0, 0);
}

// ---- bf16 LDS A-tile helpers (coarse / k_out), XOR-swizzled ----------------
__device__ __forceinline__ int swz(int row, int byte) { return byte ^ ((row & 7) << 4); }
__device__ __forceinline__ void st_a(__bf16* lds, int row, int cs, bf16x8 v) {
    *(bf16x8*)((char*)lds + swz(row, row * 512 + cs * 16)) = v;
}
__device__ __forceinline__ bf16x8 ld_a(const __bf16* lds, int row, int ka) {
    return *(const bf16x8*)((const char*)lds + swz(row, row * 512 + ka * 2));
}

template<int NT>
__device__ __forceinline__ void stage_f32(const float* __restrict__ A, long row0,
                                          __bf16* lds, int tid, long maxrow) {
    const int r0 = tid >> 5, cs = tid & 31;
    constexpr int RPI = NT / 32;
    #pragma unroll
    for (int i = 0; i < 64 / RPI; ++i) {
        int row = r0 + i * RPI;
        long gr = row0 + row; if (gr > maxrow) gr = maxrow;
        const float* p = A + gr * 256 + cs * 8;
        f32x4 x = *(const f32x4*)p, y = *(const f32x4*)(p + 4);
        st_a(lds, row, cs, cvt8(x, y));
    }
}

// 64x64-per-wave MFMA over one 256-wide K segment, A from bf16 LDS
__device__ __forceinline__ void mfma_tile(const __bf16* lds, const bf16x8* __restrict__ packB,
                                          int N, int c0, int ksb,
                                          f32x4 (&acc)[4][4], int lane) {
    const int g = lane >> 4, r15 = lane & 15;
    #pragma unroll
    for (int ks = 0; ks < 8; ++ks) {
        bf16x8 a[4];
        #pragma unroll
        for (int rt = 0; rt < 4; ++rt)
            a[rt] = ld_a(lds, rt * 16 + r15, ks * 32 + g * 8);
        const size_t kb = (size_t)((ksb + ks) * 4 + g) * N;
        #pragma unroll
        for (int ct = 0; ct < 4; ++ct) {
            bf16x8 b = packB[kb + c0 + ct * 16 + r15];
            #pragma unroll
            for (int rt = 0; rt < 4; ++rt)
                acc[rt][ct] = __builtin_amdgcn_mfma_f32_16x16x32_bf16(a[rt], b, acc[rt][ct], 0, 0, 0);
        }
    }
}

// ---------------------------------------------------------------------------
// Merged prep (R13): pack weights to b-frag layout + cvt last_inv to bf16.
// ---------------------------------------------------------------------------
__global__ __launch_bounds__(256) void k_prep(
    const float* __restrict__ W_le, const float* __restrict__ W_ce,
    const float* __restrict__ W_mlp, const float* __restrict__ last_inv,
    __bf16* __restrict__ packLE, __bf16* __restrict__ packCE,
    __bf16* __restrict__ packM, __bf16* __restrict__ li_bf)
{
    const int b = blockIdx.x, tid = threadIdx.x;
    if (b < 256) {
        int idx = b * 256 + tid, k = idx >> 8, n = idx & 255;
        packLE[(((size_t)(k >> 3) << 8) + n) * 8 + (k & 7)] = (__bf16)W_le[idx];
    } else if (b < 512) {
        int idx = (b - 256) * 256 + tid, k = idx >> 8, n = idx & 255;
        packCE[(((size_t)(k >> 3) << 8) + n) * 8 + (k & 7)] = (__bf16)W_ce[idx];
    } else if (b < 2048) {
        int idx = (b - 512) * 256 + tid, k = idx >> 9, n = idx & 511;
        packM[(((size_t)(k >> 3) << 9) + n) * 8 + (k & 7)] = (__bf16)W_mlp[idx];
    } else {
        int i = (b - 2048) * 256 + tid;
        f32x4 v = ((const f32x4*)last_inv)[i];
        bf16x4 o;
        o[0] = (__bf16)v[0]; o[1] = (__bf16)v[1]; o[2] = (__bf16)v[2]; o[3] = (__bf16)v[3];
        ((bf16x4*)li_bf)[i] = o;
    }
}

// ---------------------------------------------------------------------------
// Coarse (R13 verbatim): LE = last_equ @ W_le -> LEp, persistent, 64-row tiles.
// ---------------------------------------------------------------------------
__global__ __launch_bounds__(256) void k_coarse_equ(
    const float* __restrict__ last_equ, const bf16x8* __restrict__ packW,
    __bf16* __restrict__ LEp)
{
    __shared__ __attribute__((aligned(16))) __bf16 As[64 * 256];
    const int tid = threadIdx.x, lane = tid & 63, wid = tid >> 6;
    for (int t = blockIdx.x; t < N_COARSE * 16 / 64; t += gridDim.x) {
        stage_f32<256>(last_equ, (long)t * 64, As, tid, (long)N_COARSE * 16 - 1);
        lds_barrier();
        f32x4 acc[4][4] = {};
        mfma_tile(As, packW, 256, wid * 64, 0, acc, lane);
        #pragma unroll
        for (int rt = 0; rt < 4; ++rt) {
            int coarse = t * 4 + rt;
            #pragma unroll
            for (int ct = 0; ct < 4; ++ct) {
                int cg = wid * 4 + ct;
                bf16x4 v;
                v[0] = (__bf16)acc[rt][ct][0]; v[1] = (__bf16)acc[rt][ct][1];
                v[2] = (__bf16)acc[rt][ct][2]; v[3] = (__bf16)acc[rt][ct][3];
                *(bf16x4*)(LEp + ((size_t)(coarse * 16 + cg) * 64 + lane) * 4) = v;
            }
        }
        lds_barrier();
    }
}

// ---------------------------------------------------------------------------
// Fine fused, DMA-pipelined: 32-row f32 double-buffer (2 x 32 KB) filled by
// global_load_lds. Per iteration: vmcnt(0) [pre-drained by prior compute] ->
// barrier -> issue next tile's DMA (fire-and-forget, zero VGPR) -> MFMA on
// current buffer (f32 LDS read + cvt at read) -> LE gather/product/mean.
// Stage of t+1 overlaps compute of t: VMEM stays fed through the MFMA phase
// (the R16-diagnosed stage|compute exclusivity, fixed without the register
// cost that killed R4/R9). Source addresses are inverse-XOR-swizzled so the
// linear DMA produces a conflict-mitigated LDS layout (rule: both-sides).
// ---------------------------------------------------------------------------
__global__ __launch_bounds__(256) void k_fine_equ(
    const float* __restrict__ cur_equ, const bf16x8* __restrict__ packW,
    const __bf16* __restrict__ LEp, const int* __restrict__ up,
    __bf16* __restrict__ equ)
{
    __shared__ __attribute__((aligned(16))) float Af[2][32 * 256];
    const int tid = threadIdx.x, lane = tid & 63, wid = tid >> 6;
    const int g = lane >> 4, r15 = lane & 15;
    const int NT = N_FINE / 2;                               // 25000 tiles
    const int per = (NT + gridDim.x - 1) / gridDim.x;
    const int tb = blockIdx.x * per;
    const int te = min(tb + per, NT);
    if (tb >= te) return;

    // lane's source float-offset within a row: 32B chunk (lane>>1)^(row&7),
    // 16B half (lane&1) -> lands at linear LDS slot lane*16B.
    const int lhalf = (lane & 1) << 2;

    // prologue: DMA tile tb into buf[tb&1]
    {
        const float* rb = cur_equ + (size_t)tb * 32 * 256;
        #pragma unroll
        for (int i = 0; i < 8; ++i) {
            int row = wid * 8 + i;
            gl_lds16(rb + (size_t)row * 256 + ((((lane >> 1) ^ (row & 7)) << 3) + lhalf),
                     &Af[tb & 1][row * 256]);
        }
    }

    for (int t = tb; t < te; ++t) {
        asm volatile("s_waitcnt vmcnt(0)" ::: "memory");   // t's DMA done (pre-drained)
        __builtin_amdgcn_s_barrier();

        // issue next tile's DMA into the other buffer; overlaps compute below.
        // Safe: readers of that buffer finished before the barrier above.
        if (t + 1 < te) {
            const float* rb = cur_equ + (size_t)(t + 1) * 32 * 256;
            #pragma unroll
            for (int i = 0; i < 8; ++i) {
                int row = wid * 8 + i;
                gl_lds16(rb + (size_t)row * 256 + ((((lane >> 1) ^ (row & 7)) << 3) + lhalf),
                         &Af[(t + 1) & 1][row * 256]);
            }
        }

        // ---- CE = cur_equ tile @ W_ce (A from f32 LDS, cvt at read) ----
        const float* B = Af[t & 1];
        f32x4 acc[2][4] = {};
        #pragma unroll
        for (int ks = 0; ks < 8; ++ks) {
            bf16x8 a[2];
            #pragma unroll
            for (int rt = 0; rt < 2; ++rt) {
                int r = rt * 16 + r15;
                const float* p = B + r * 256 + (((4 * ks + g) ^ (r & 7)) << 3);
                a[rt] = cvt8(*(const f32x4*)p, *(const f32x4*)(p + 4));
            }
            const size_t kb = (size_t)(ks * 4 + g) * 256;
            #pragma unroll
            for (int ct = 0; ct < 4; ++ct) {
                bf16x8 b = packW[kb + wid * 64 + ct * 16 + r15];
                #pragma unroll
                for (int rt = 0; rt < 2; ++rt)
                    acc[rt][ct] = __builtin_amdgcn_mfma_f32_16x16x32_bf16(a[rt], b, acc[rt][ct], 0, 0, 0);
            }
        }

        // ---- LE gathers (post-MFMA), product, basis-mean, store ----
        const int n0 = t * 2;
        const int cu0 = up[n0], cu1 = up[n0 + 1];          // uniform -> s_load
        bf16x4 le[2][4];
        #pragma unroll
        for (int ct = 0; ct < 4; ++ct) {
            le[0][ct] = *(const bf16x4*)(LEp + ((size_t)(cu0 * 16 + wid * 4 + ct) * 64 + lane) * 4);
            le[1][ct] = *(const bf16x4*)(LEp + ((size_t)(cu1 * 16 + wid * 4 + ct) * 64 + lane) * 4);
        }
        #pragma unroll
        for (int rt = 0; rt < 2; ++rt) {
            #pragma unroll
            for (int ct = 0; ct < 4; ++ct) {
                float s = acc[rt][ct][0] * (float)le[rt][ct][0]
                        + acc[rt][ct][1] * (float)le[rt][ct][1]
                        + acc[rt][ct][2] * (float)le[rt][ct][2]
                        + acc[rt][ct][3] * (float)le[rt][ct][3];
                s += __shfl_xor(s, 16, 64);   // basis reduce over lane bit 4
                s += __shfl_xor(s, 32, 64);   // basis reduce over lane bit 5
                if (lane < 16)
                    equ[(size_t)(n0 + rt) * 256 + wid * 64 + ct * 16 + lane] =
                        (__bf16)(s * 0.0625f);
            }
        }
        // no end barrier: next iteration's vmcnt(0)+barrier precedes any
        // DMA overwrite of the buffer read in this iteration.
    }
}

// ---------------------------------------------------------------------------
// Output (R13 one-shot): out = [ last_inv[up] | cur_inv | equ ] @ W_mlp.
// ---------------------------------------------------------------------------
__global__ __launch_bounds__(512) void k_out(
    const __bf16* __restrict__ li_bf, const float* __restrict__ cur_inv,
    const __bf16* __restrict__ equ, const bf16x8* __restrict__ packW,
    const int* __restrict__ up, float* __restrict__ out)
{
    __shared__ __attribute__((aligned(16))) __bf16 As[64 * 256];
    const int tid = threadIdx.x, lane = tid & 63, wid = tid >> 6;
    const int row0 = blockIdx.x * 64;
    const int c0 = wid * 64;
    const int r0 = tid >> 5, cs = tid & 31;
    f32x4 acc[4][4] = {};

    #pragma unroll
    for (int i = 0; i < 4; ++i) {
        int row = r0 + i * 16;
        int gr = row0 + row; if (gr > N_FINE - 1) gr = N_FINE - 1;
        st_a(As, row, cs, *(const bf16x8*)(li_bf + (size_t)up[gr] * 256 + cs * 8));
    }
    lds_barrier();
    mfma_tile(As, packW, 512, c0, 0, acc, lane);
    lds_barrier();

    stage_f32<512>(cur_inv, row0, As, tid, N_FINE - 1);
    lds_barrier();
    mfma_tile(As, packW, 512, c0, 8, acc, lane);
    lds_barrier();

    #pragma unroll
    for (int i = 0; i < 4; ++i) {
        int row = r0 + i * 16;
        int gr = row0 + row; if (gr > N_FINE - 1) gr = N_FINE - 1;
        st_a(As, row, cs, *(const bf16x8*)(equ + (size_t)gr * 256 + cs * 8));
    }
    lds_barrier();
    mfma_tile(As, packW, 512, c0, 16, acc, lane);

    const int g = lane >> 4, r15 = lane & 15;
    #pragma unroll
    for (int rt = 0; rt < 4; ++rt)
        #pragma unroll
        for (int j = 0; j < 4; ++j) {
            int r = row0 + rt * 16 + g * 4 + j;
            if (r < N_FINE)
                #pragma unroll
                for (int ct = 0; ct < 4; ++ct)
                    out[(size_t)r * 512 + c0 + ct * 16 + r15] = acc[rt][ct][j];
        }
}

extern "C" void kernel_launch(void* const* d_in, const int* in_sizes, int n_in,
                              void* d_out, int out_size, void* d_ws, size_t ws_size,
                              hipStream_t stream) {
    const float* last_inv = (const float*)d_in[0];
    const float* cur_inv  = (const float*)d_in[1];
    const float* last_equ = (const float*)d_in[2];
    const float* cur_equ  = (const float*)d_in[3];
    const int*   up       = (const int*)d_in[4];
    const float* W_le     = (const float*)d_in[5];
    const float* W_ce     = (const float*)d_in[6];
    const float* W_mlp    = (const float*)d_in[7];
    float* out = (float*)d_out;

    // workspace carve-up (~135 MB)
    char* w = (char*)d_ws;
    __bf16* LEp    = (__bf16*)w;  w += (size_t)N_COARSE * 16 * 256 * 2;  // 102.4 MB
    __bf16* equ    = (__bf16*)w;  w += (size_t)N_FINE * 256 * 2;        //  25.6 MB
    __bf16* li_bf  = (__bf16*)w;  w += (size_t)N_COARSE * 256 * 2;      //   6.4 MB
    __bf16* packLE = (__bf16*)w;  w += (size_t)256 * 256 * 2;
    __bf16* packCE = (__bf16*)w;  w += (size_t)256 * 256 * 2;
    __bf16* packM  = (__bf16*)w;  w += (size_t)768 * 512 * 2;

    k_prep<<<2048 + 3125, 256, 0, stream>>>(
        W_le, W_ce, W_mlp, last_inv, packLE, packCE, packM, li_bf);

    // coarse: R13 persistent (5 blocks/CU)
    k_coarse_equ<<<1280, 256, 0, stream>>>(
        last_equ, (const bf16x8*)packLE, LEp);

    // fine: DMA-pipelined persistent, 64 KB LDS -> 2 blocks/CU x 256 CUs
    k_fine_equ<<<512, 256, 0, stream>>>(
        cur_equ, (const bf16x8*)packCE, LEp, up, equ);

    k_out<<<(N_FINE + 63) / 64, 512, 0, stream>>>(
        li_bf, cur_inv, equ, (const bf16x8*)packM, up, out);
}

// Round 18
// 483.394 us; speedup vs baseline: 1.6307x; 1.0683x over previous
//
#include <hip/hip_runtime.h>
#include <hip/hip_bf16.h>

#define N_COARSE 12500
#define N_FINE   50000

typedef __bf16 bf16x8 __attribute__((ext_vector_type(8)));
typedef __bf16 bf16x4 __attribute__((ext_vector_type(4)));
typedef float  f32x4  __attribute__((ext_vector_type(4)));

// ---------------------------------------------------------------------------
// Fragment conventions (v_mfma_f32_16x16x32_bf16), HW-verified:
//   a-frag: lane holds A[row = lane&15][k = (lane>>4)*8 + j]
//   b-frag: lane holds B[k = (lane>>4)*8 + j][col = lane&15]
//   d     : lane holds D[row = (lane>>4)*4 + j][col = lane&15]
// ---------------------------------------------------------------------------

__device__ __forceinline__ bf16x8 cvt8(f32x4 x, f32x4 y) {
    bf16x8 r;
    r[0] = (__bf16)x[0]; r[1] = (__bf16)x[1]; r[2] = (__bf16)x[2]; r[3] = (__bf16)x[3];
    r[4] = (__bf16)y[0]; r[5] = (__bf16)y[1]; r[6] = (__bf16)y[2]; r[7] = (__bf16)y[3];
    return r;
}

// Barrier with LDS-only fence (avoids __syncthreads' vmcnt(0) drain).
__device__ __forceinline__ void lds_barrier() {
    asm volatile("s_waitcnt lgkmcnt(0)" ::: "memory");
    __builtin_amdgcn_s_barrier();
}

// async global->LDS DMA, 16B per lane; LDS dest = uniform base + lane*16
__device__ __forceinline__ void gl_lds16(const float* g, float* l) {
    __builtin_amdgcn_global_load_lds(
        (const __attribute__((address_space(1))) void*)g,
        (__attribute__((address_space(3))) void*)l, 16, 0, 0);
}

// ---- bf16 LDS A-tile helpers (k_out), XOR-swizzled -------------------------
__device__ __forceinline__ int swz(int row, int byte) { return byte ^ ((row & 7) << 4); }
__device__ __forceinline__ void st_a(__bf16* lds, int row, int cs, bf16x8 v) {
    *(bf16x8*)((char*)lds + swz(row, row * 512 + cs * 16)) = v;
}
__device__ __forceinline__ bf16x8 ld_a(const __bf16* lds, int row, int ka) {
    return *(const bf16x8*)((const char*)lds + swz(row, row * 512 + ka * 2));
}

template<int NT>
__device__ __forceinline__ void stage_f32(const float* __restrict__ A, long row0,
                                          __bf16* lds, int tid, long maxrow) {
    const int r0 = tid >> 5, cs = tid & 31;
    constexpr int RPI = NT / 32;
    #pragma unroll
    for (int i = 0; i < 64 / RPI; ++i) {
        int row = r0 + i * RPI;
        long gr = row0 + row; if (gr > maxrow) gr = maxrow;
        const float* p = A + gr * 256 + cs * 8;
        f32x4 x = *(const f32x4*)p, y = *(const f32x4*)(p + 4);
        st_a(lds, row, cs, cvt8(x, y));
    }
}

// 64x64-per-wave MFMA over one 256-wide K segment, A from bf16 LDS (k_out)
__device__ __forceinline__ void mfma_tile(const __bf16* lds, const bf16x8* __restrict__ packB,
                                          int N, int c0, int ksb,
                                          f32x4 (&acc)[4][4], int lane) {
    const int g = lane >> 4, r15 = lane & 15;
    #pragma unroll
    for (int ks = 0; ks < 8; ++ks) {
        bf16x8 a[4];
        #pragma unroll
        for (int rt = 0; rt < 4; ++rt)
            a[rt] = ld_a(lds, rt * 16 + r15, ks * 32 + g * 8);
        const size_t kb = (size_t)((ksb + ks) * 4 + g) * N;
        #pragma unroll
        for (int ct = 0; ct < 4; ++ct) {
            bf16x8 b = packB[kb + c0 + ct * 16 + r15];
            #pragma unroll
            for (int rt = 0; rt < 4; ++rt)
                acc[rt][ct] = __builtin_amdgcn_mfma_f32_16x16x32_bf16(a[rt], b, acc[rt][ct], 0, 0, 0);
        }
    }
}

// ---------------------------------------------------------------------------
// Merged prep (R13): pack weights to b-frag layout + cvt last_inv to bf16.
// ---------------------------------------------------------------------------
__global__ __launch_bounds__(256) void k_prep(
    const float* __restrict__ W_le, const float* __restrict__ W_ce,
    const float* __restrict__ W_mlp, const float* __restrict__ last_inv,
    __bf16* __restrict__ packLE, __bf16* __restrict__ packCE,
    __bf16* __restrict__ packM, __bf16* __restrict__ li_bf)
{
    const int b = blockIdx.x, tid = threadIdx.x;
    if (b < 256) {
        int idx = b * 256 + tid, k = idx >> 8, n = idx & 255;
        packLE[(((size_t)(k >> 3) << 8) + n) * 8 + (k & 7)] = (__bf16)W_le[idx];
    } else if (b < 512) {
        int idx = (b - 256) * 256 + tid, k = idx >> 8, n = idx & 255;
        packCE[(((size_t)(k >> 3) << 8) + n) * 8 + (k & 7)] = (__bf16)W_ce[idx];
    } else if (b < 2048) {
        int idx = (b - 512) * 256 + tid, k = idx >> 9, n = idx & 511;
        packM[(((size_t)(k >> 3) << 9) + n) * 8 + (k & 7)] = (__bf16)W_mlp[idx];
    } else {
        int i = (b - 2048) * 256 + tid;
        f32x4 v = ((const f32x4*)last_inv)[i];
        bf16x4 o;
        o[0] = (__bf16)v[0]; o[1] = (__bf16)v[1]; o[2] = (__bf16)v[2]; o[3] = (__bf16)v[3];
        ((bf16x4*)li_bf)[i] = o;
    }
}

// ---------------------------------------------------------------------------
// Coarse, DMA-pipelined (R17 fine template ported): LE = last_equ @ W_le.
// 32-row f32 double-buffer (2 x 32 KB) filled by global_load_lds with
// inverse-XOR-swizzled source; per iteration: vmcnt(0) [pre-drained by the
// previous compute] -> barrier -> issue next tile's DMA -> MFMA (cvt at
// read) -> LEp store. Zero prefetch VGPRs; stage(t+1) overlaps compute(t).
// ---------------------------------------------------------------------------
__global__ __launch_bounds__(256) void k_coarse_equ(
    const float* __restrict__ last_equ, const bf16x8* __restrict__ packW,
    __bf16* __restrict__ LEp)
{
    __shared__ __attribute__((aligned(16))) float Af[2][32 * 256];
    const int tid = threadIdx.x, lane = tid & 63, wid = tid >> 6;
    const int g = lane >> 4, r15 = lane & 15;
    const int NT = N_COARSE * 16 / 32;                       // 6250 tiles
    const int per = (NT + gridDim.x - 1) / gridDim.x;
    const int tb = blockIdx.x * per;
    const int te = min(tb + per, NT);
    if (tb >= te) return;

    const int lhalf = (lane & 1) << 2;   // 16B half within 32B chunk

    // prologue: DMA tile tb
    {
        const float* rb = last_equ + (size_t)tb * 32 * 256;
        #pragma unroll
        for (int i = 0; i < 8; ++i) {
            int row = wid * 8 + i;
            gl_lds16(rb + (size_t)row * 256 + ((((lane >> 1) ^ (row & 7)) << 3) + lhalf),
                     &Af[tb & 1][row * 256]);
        }
    }

    for (int t = tb; t < te; ++t) {
        asm volatile("s_waitcnt vmcnt(0)" ::: "memory");
        __builtin_amdgcn_s_barrier();

        if (t + 1 < te) {
            const float* rb = last_equ + (size_t)(t + 1) * 32 * 256;
            #pragma unroll
            for (int i = 0; i < 8; ++i) {
                int row = wid * 8 + i;
                gl_lds16(rb + (size_t)row * 256 + ((((lane >> 1) ^ (row & 7)) << 3) + lhalf),
                         &Af[(t + 1) & 1][row * 256]);
            }
        }

        const float* B = Af[t & 1];
        f32x4 acc[2][4] = {};
        #pragma unroll
        for (int ks = 0; ks < 8; ++ks) {
            bf16x8 a[2];
            #pragma unroll
            for (int rt = 0; rt < 2; ++rt) {
                int r = rt * 16 + r15;
                const float* p = B + r * 256 + (((4 * ks + g) ^ (r & 7)) << 3);
                a[rt] = cvt8(*(const f32x4*)p, *(const f32x4*)(p + 4));
            }
            const size_t kb = (size_t)(ks * 4 + g) * 256;
            #pragma unroll
            for (int ct = 0; ct < 4; ++ct) {
                bf16x8 b = packW[kb + wid * 64 + ct * 16 + r15];
                #pragma unroll
                for (int rt = 0; rt < 2; ++rt)
                    acc[rt][ct] = __builtin_amdgcn_mfma_f32_16x16x32_bf16(a[rt], b, acc[rt][ct], 0, 0, 0);
            }
        }

        #pragma unroll
        for (int rt = 0; rt < 2; ++rt) {
            int coarse = t * 2 + rt;
            #pragma unroll
            for (int ct = 0; ct < 4; ++ct) {
                int cg = wid * 4 + ct;
                bf16x4 v;
                v[0] = (__bf16)acc[rt][ct][0]; v[1] = (__bf16)acc[rt][ct][1];
                v[2] = (__bf16)acc[rt][ct][2]; v[3] = (__bf16)acc[rt][ct][3];
                *(bf16x4*)(LEp + ((size_t)(coarse * 16 + cg) * 64 + lane) * 4) = v;
            }
        }
        // no end barrier: next iteration's vmcnt(0)+barrier precedes any DMA
        // overwrite of the buffer read here.
    }
}

// ---------------------------------------------------------------------------
// Fine fused, DMA-pipelined (R17, best measured) — unchanged.
// ---------------------------------------------------------------------------
__global__ __launch_bounds__(256) void k_fine_equ(
    const float* __restrict__ cur_equ, const bf16x8* __restrict__ packW,
    const __bf16* __restrict__ LEp, const int* __restrict__ up,
    __bf16* __restrict__ equ)
{
    __shared__ __attribute__((aligned(16))) float Af[2][32 * 256];
    const int tid = threadIdx.x, lane = tid & 63, wid = tid >> 6;
    const int g = lane >> 4, r15 = lane & 15;
    const int NT = N_FINE / 2;                               // 25000 tiles
    const int per = (NT + gridDim.x - 1) / gridDim.x;
    const int tb = blockIdx.x * per;
    const int te = min(tb + per, NT);
    if (tb >= te) return;

    const int lhalf = (lane & 1) << 2;

    {
        const float* rb = cur_equ + (size_t)tb * 32 * 256;
        #pragma unroll
        for (int i = 0; i < 8; ++i) {
            int row = wid * 8 + i;
            gl_lds16(rb + (size_t)row * 256 + ((((lane >> 1) ^ (row & 7)) << 3) + lhalf),
                     &Af[tb & 1][row * 256]);
        }
    }

    for (int t = tb; t < te; ++t) {
        asm volatile("s_waitcnt vmcnt(0)" ::: "memory");
        __builtin_amdgcn_s_barrier();

        if (t + 1 < te) {
            const float* rb = cur_equ + (size_t)(t + 1) * 32 * 256;
            #pragma unroll
            for (int i = 0; i < 8; ++i) {
                int row = wid * 8 + i;
                gl_lds16(rb + (size_t)row * 256 + ((((lane >> 1) ^ (row & 7)) << 3) + lhalf),
                         &Af[(t + 1) & 1][row * 256]);
            }
        }

        const float* B = Af[t & 1];
        f32x4 acc[2][4] = {};
        #pragma unroll
        for (int ks = 0; ks < 8; ++ks) {
            bf16x8 a[2];
            #pragma unroll
            for (int rt = 0; rt < 2; ++rt) {
                int r = rt * 16 + r15;
                const float* p = B + r * 256 + (((4 * ks + g) ^ (r & 7)) << 3);
                a[rt] = cvt8(*(const f32x4*)p, *(const f32x4*)(p + 4));
            }
            const size_t kb = (size_t)(ks * 4 + g) * 256;
            #pragma unroll
            for (int ct = 0; ct < 4; ++ct) {
                bf16x8 b = packW[kb + wid * 64 + ct * 16 + r15];
                #pragma unroll
                for (int rt = 0; rt < 2; ++rt)
                    acc[rt][ct] = __builtin_amdgcn_mfma_f32_16x16x32_bf16(a[rt], b, acc[rt][ct], 0, 0, 0);
            }
        }

        const int n0 = t * 2;
        const int cu0 = up[n0], cu1 = up[n0 + 1];
        bf16x4 le[2][4];
        #pragma unroll
        for (int ct = 0; ct < 4; ++ct) {
            le[0][ct] = *(const bf16x4*)(LEp + ((size_t)(cu0 * 16 + wid * 4 + ct) * 64 + lane) * 4);
            le[1][ct] = *(const bf16x4*)(LEp + ((size_t)(cu1 * 16 + wid * 4 + ct) * 64 + lane) * 4);
        }
        #pragma unroll
        for (int rt = 0; rt < 2; ++rt) {
            #pragma unroll
            for (int ct = 0; ct < 4; ++ct) {
                float s = acc[rt][ct][0] * (float)le[rt][ct][0]
                        + acc[rt][ct][1] * (float)le[rt][ct][1]
                        + acc[rt][ct][2] * (float)le[rt][ct][2]
                        + acc[rt][ct][3] * (float)le[rt][ct][3];
                s += __shfl_xor(s, 16, 64);
                s += __shfl_xor(s, 32, 64);
                if (lane < 16)
                    equ[(size_t)(n0 + rt) * 256 + wid * 64 + ct * 16 + lane] =
                        (__bf16)(s * 0.0625f);
            }
        }
    }
}

// ---------------------------------------------------------------------------
// Output (R13 one-shot): out = [ last_inv[up] | cur_inv | equ ] @ W_mlp.
// ---------------------------------------------------------------------------
__global__ __launch_bounds__(512) void k_out(
    const __bf16* __restrict__ li_bf, const float* __restrict__ cur_inv,
    const __bf16* __restrict__ equ, const bf16x8* __restrict__ packW,
    const int* __restrict__ up, float* __restrict__ out)
{
    __shared__ __attribute__((aligned(16))) __bf16 As[64 * 256];
    const int tid = threadIdx.x, lane = tid & 63, wid = tid >> 6;
    const int row0 = blockIdx.x * 64;
    const int c0 = wid * 64;
    const int r0 = tid >> 5, cs = tid & 31;
    f32x4 acc[4][4] = {};

    #pragma unroll
    for (int i = 0; i < 4; ++i) {
        int row = r0 + i * 16;
        int gr = row0 + row; if (gr > N_FINE - 1) gr = N_FINE - 1;
        st_a(As, row, cs, *(const bf16x8*)(li_bf + (size_t)up[gr] * 256 + cs * 8));
    }
    lds_barrier();
    mfma_tile(As, packW, 512, c0, 0, acc, lane);
    lds_barrier();

    stage_f32<512>(cur_inv, row0, As, tid, N_FINE - 1);
    lds_barrier();
    mfma_tile(As, packW, 512, c0, 8, acc, lane);
    lds_barrier();

    #pragma unroll
    for (int i = 0; i < 4; ++i) {
        int row = r0 + i * 16;
        int gr = row0 + row; if (gr > N_FINE - 1) gr = N_FINE - 1;
        st_a(As, row, cs, *(const bf16x8*)(equ + (size_t)gr * 256 + cs * 8));
    }
    lds_barrier();
    mfma_tile(As, packW, 512, c0, 16, acc, lane);

    const int g = lane >> 4, r15 = lane & 15;
    #pragma unroll
    for (int rt = 0; rt < 4; ++rt)
        #pragma unroll
        for (int j = 0; j < 4; ++j) {
            int r = row0 + rt * 16 + g * 4 + j;
            if (r < N_FINE)
                #pragma unroll
                for (int ct = 0; ct < 4; ++ct)
                    out[(size_t)r * 512 + c0 + ct * 16 + r15] = acc[rt][ct][j];
        }
}

extern "C" void kernel_launch(void* const* d_in, const int* in_sizes, int n_in,
                              void* d_out, int out_size, void* d_ws, size_t ws_size,
                              hipStream_t stream) {
    const float* last_inv = (const float*)d_in[0];
    const float* cur_inv  = (const float*)d_in[1];
    const float* last_equ = (const float*)d_in[2];
    const float* cur_equ  = (const float*)d_in[3];
    const int*   up       = (const int*)d_in[4];
    const float* W_le     = (const float*)d_in[5];
    const float* W_ce     = (const float*)d_in[6];
    const float* W_mlp    = (const float*)d_in[7];
    float* out = (float*)d_out;

    // workspace carve-up (~135 MB)
    char* w = (char*)d_ws;
    __bf16* LEp    = (__bf16*)w;  w += (size_t)N_COARSE * 16 * 256 * 2;  // 102.4 MB
    __bf16* equ    = (__bf16*)w;  w += (size_t)N_FINE * 256 * 2;        //  25.6 MB
    __bf16* li_bf  = (__bf16*)w;  w += (size_t)N_COARSE * 256 * 2;      //   6.4 MB
    __bf16* packLE = (__bf16*)w;  w += (size_t)256 * 256 * 2;
    __bf16* packCE = (__bf16*)w;  w += (size_t)256 * 256 * 2;
    __bf16* packM  = (__bf16*)w;  w += (size_t)768 * 512 * 2;

    k_prep<<<2048 + 3125, 256, 0, stream>>>(
        W_le, W_ce, W_mlp, last_inv, packLE, packCE, packM, li_bf);

    // coarse: DMA-pipelined persistent, 64 KB LDS -> 2 blocks/CU x 256 CUs
    k_coarse_equ<<<512, 256, 0, stream>>>(
        last_equ, (const bf16x8*)packLE, LEp);

    // fine: DMA-pipelined persistent (R17, best measured)
    k_fine_equ<<<512, 256, 0, stream>>>(
        cur_equ, (const bf16x8*)packCE, LEp, up, equ);

    k_out<<<(N_FINE + 63) / 64, 512, 0, stream>>>(
        li_bf, cur_inv, equ, (const bf16x8*)packM, up, out);
}